// Round 1
// baseline (243.541 us; speedup 1.0000x reference)
//
#include <hip/hip_runtime.h>
#include <math.h>

#define T_DIM 2048
#define B_DIM 4
#define BT (B_DIM * T_DIM)
#define MODEL 512
#define OUTF 256
#define WSZ 16
#define WIN 33

// out[row, o] = sum_m in[row,m] * W[m,o] + bias[o]   (bias may be null)
// 8 rows per block; x rows staged in LDS, read back as broadcast float4
// so the ds_read:FMA ratio is 1:4 per row.
template <int K>
__global__ __launch_bounds__(256) void rowgemm_kernel(
    const float* __restrict__ in, const float* __restrict__ W,
    const float* __restrict__ bias, float* __restrict__ out) {
  __shared__ float sx[8][K];
  const int tid = threadIdx.x;
  const int row0 = blockIdx.x * 8;

  const float4* gin = (const float4*)(in + (size_t)row0 * K);
  float4* s4 = (float4*)&sx[0][0];
  for (int i = tid; i < 8 * K / 4; i += 256) s4[i] = gin[i];
  __syncthreads();

  float acc[8] = {0};
  const int o = tid;
  for (int mc = 0; mc < K / 4; ++mc) {
    const float w0 = W[(4 * mc + 0) * OUTF + o];
    const float w1 = W[(4 * mc + 1) * OUTF + o];
    const float w2 = W[(4 * mc + 2) * OUTF + o];
    const float w3 = W[(4 * mc + 3) * OUTF + o];
#pragma unroll
    for (int r = 0; r < 8; ++r) {
      const float4 xv = *(const float4*)&sx[r][4 * mc];
      acc[r] = fmaf(xv.x, w0, acc[r]);
      acc[r] = fmaf(xv.y, w1, acc[r]);
      acc[r] = fmaf(xv.z, w2, acc[r]);
      acc[r] = fmaf(xv.w, w3, acc[r]);
    }
  }
  const float bb = bias ? bias[o] : 0.f;
#pragma unroll
  for (int r = 0; r < 8; ++r)
    out[(size_t)(row0 + r) * OUTF + o] = acc[r] + bb;
}

// One block per (b,t). scores -> softmax -> weighted.
__global__ __launch_bounds__(256) void attn_kernel(
    const float* __restrict__ xWh,    // [BT,256], b_attn already folded in
    const float* __restrict__ encWe,  // [BT,256]
    const float* __restrict__ enc,    // [BT,256]
    const float* __restrict__ v,      // [256]
    float* __restrict__ weighted,     // [BT,256]
    float* __restrict__ a_out) {      // [BT,33]
  __shared__ float s_xwh[OUTF];
  __shared__ float s_v[OUTF];
  __shared__ float s_sc[WIN];
  __shared__ float s_a[WIN];

  const int tid = threadIdx.x;
  const int bt = blockIdx.x;
  const int b = bt / T_DIM, t = bt % T_DIM;

  s_xwh[tid] = xWh[(size_t)bt * OUTF + tid];
  s_v[tid] = v[tid];
  __syncthreads();

  // scores: each wave handles w = wv, wv+4, ...; lane sums 4 o-values.
  const int wv = tid >> 6, lane = tid & 63;
  for (int w = wv; w < WIN; w += 4) {
    const int t2 = t + w - WSZ;
    float acc = 0.f;
    if (t2 >= 0 && t2 < T_DIM) {
      const float* er = encWe + (size_t)(b * T_DIM + t2) * OUTF;
#pragma unroll
      for (int k = 0; k < 4; ++k) {
        const int o = lane + 64 * k;
        acc += tanhf(s_xwh[o] + er[o]) * s_v[o];
      }
    } else {
#pragma unroll
      for (int k = 0; k < 4; ++k) {
        const int o = lane + 64 * k;
        acc += tanhf(s_xwh[o]) * s_v[o];  // window row is zero-padded
      }
    }
#pragma unroll
    for (int off = 32; off; off >>= 1) acc += __shfl_xor(acc, off);
    if (lane == 0) s_sc[w] = acc;
  }
  __syncthreads();

  // softmax over 33 in wave 0
  if (tid < 64) {
    const float sc = (tid < WIN) ? s_sc[tid] : -INFINITY;
    float m = sc;
#pragma unroll
    for (int off = 32; off; off >>= 1) m = fmaxf(m, __shfl_xor(m, off));
    float e = (tid < WIN) ? __expf(sc - m) : 0.f;
    float s = e;
#pragma unroll
    for (int off = 32; off; off >>= 1) s += __shfl_xor(s, off);
    const float av = e / s;
    if (tid < WIN) {
      s_a[tid] = av;
      a_out[(size_t)bt * WIN + tid] = av;
    }
  }
  __syncthreads();

  // weighted[f] = sum_w a[w] * enc[b, t+w-16, f]
  float acc = 0.f;
#pragma unroll
  for (int w = 0; w < WIN; ++w) {
    const int t2 = t + w - WSZ;
    if (t2 >= 0 && t2 < T_DIM)
      acc = fmaf(s_a[w], enc[(size_t)(b * T_DIM + t2) * OUTF + tid], acc);
  }
  weighted[(size_t)bt * OUTF + tid] = acc;
}

// out = sigmoid([x | weighted] @ W_lin + b_lin), 8 rows per block.
__global__ __launch_bounds__(256) void final_kernel(
    const float* __restrict__ x,    // [BT,512]
    const float* __restrict__ wtd,  // [BT,256]
    const float* __restrict__ Wl,   // [768,256]
    const float* __restrict__ bl,   // [256]
    float* __restrict__ out) {      // [BT,256]
  __shared__ float sh[8][MODEL + OUTF];
  const int tid = threadIdx.x;
  const int row0 = blockIdx.x * 8;

  for (int i = tid; i < 8 * MODEL / 4; i += 256) {
    const int r = i >> 7, c = i & 127;
    ((float4*)&sh[r][0])[c] = ((const float4*)(x + (size_t)(row0 + r) * MODEL))[c];
  }
  for (int i = tid; i < 8 * OUTF / 4; i += 256) {
    const int r = i >> 6, c = i & 63;
    ((float4*)&sh[r][MODEL])[c] = ((const float4*)(wtd + (size_t)(row0 + r) * OUTF))[c];
  }
  __syncthreads();

  float acc[8] = {0};
  const int o = tid;
  for (int kc = 0; kc < (MODEL + OUTF) / 4; ++kc) {
    const float w0 = Wl[(4 * kc + 0) * OUTF + o];
    const float w1 = Wl[(4 * kc + 1) * OUTF + o];
    const float w2 = Wl[(4 * kc + 2) * OUTF + o];
    const float w3 = Wl[(4 * kc + 3) * OUTF + o];
#pragma unroll
    for (int r = 0; r < 8; ++r) {
      const float4 hv = *(const float4*)&sh[r][4 * kc];
      acc[r] = fmaf(hv.x, w0, acc[r]);
      acc[r] = fmaf(hv.y, w1, acc[r]);
      acc[r] = fmaf(hv.z, w2, acc[r]);
      acc[r] = fmaf(hv.w, w3, acc[r]);
    }
  }
  const float bb = bl[o];
#pragma unroll
  for (int r = 0; r < 8; ++r) {
    const float z = acc[r] + bb;
    out[(size_t)(row0 + r) * OUTF + o] = 1.f / (1.f + __expf(-z));
  }
}

extern "C" void kernel_launch(void* const* d_in, const int* in_sizes, int n_in,
                              void* d_out, int out_size, void* d_ws,
                              size_t ws_size, hipStream_t stream) {
  const float* x      = (const float*)d_in[0];  // [4,2048,512]
  const float* enc    = (const float*)d_in[1];  // [4,2048,256]
  const float* W_attn = (const float*)d_in[2];  // [768,256]
  const float* b_attn = (const float*)d_in[3];  // [256]
  const float* v      = (const float*)d_in[4];  // [256]
  const float* W_lin  = (const float*)d_in[5];  // [768,256]
  const float* b_lin  = (const float*)d_in[6];  // [256]

  float* out   = (float*)d_out;                  // [BT,256]
  float* a_out = out + (size_t)BT * OUTF;        // [BT,33]

  // workspace: 3 fp32 intermediates of [BT,256] = 24 MB total
  float* xWh   = (float*)d_ws;
  float* encWe = xWh + (size_t)BT * OUTF;
  float* wtd   = encWe + (size_t)BT * OUTF;

  // xWh = x @ W_attn[:512] + b_attn
  rowgemm_kernel<MODEL><<<BT / 8, 256, 0, stream>>>(x, W_attn, b_attn, xWh);
  // encWe = enc @ W_attn[512:]
  rowgemm_kernel<OUTF><<<BT / 8, 256, 0, stream>>>(enc, W_attn + MODEL * OUTF,
                                                   nullptr, encWe);
  // scores -> softmax -> weighted (also writes `a` output)
  attn_kernel<<<BT, 256, 0, stream>>>(xWh, encWe, enc, v, wtd, a_out);
  // out = sigmoid([x|weighted] @ W_lin + b_lin)
  final_kernel<<<BT / 8, 256, 0, stream>>>(x, wtd, W_lin, b_lin, out);
}

// Round 2
// 151.317 us; speedup vs baseline: 1.6095x; 1.6095x over previous
//
#include <hip/hip_runtime.h>
#include <math.h>

#define T_DIM 2048
#define B_DIM 4
#define BT (B_DIM * T_DIM)
#define MODEL 512
#define OUTF 256
#define WSZ 16
#define WIN 33

typedef __attribute__((ext_vector_type(8))) short bf16x8;
typedef __attribute__((ext_vector_type(4))) float f32x4;

__device__ inline unsigned short f2bf(float f) {
  unsigned int u = __float_as_uint(f);
  u += 0x7fffu + ((u >> 16) & 1u);  // RNE
  return (unsigned short)(u >> 16);
}
__device__ inline float bf2f(unsigned short u) {
  return __uint_as_float(((unsigned int)u) << 16);
}
__device__ inline float fast_tanh(float y) {
  // tanh(y) = 1 - 2/(e^{2y}+1); exp inf/0 saturate correctly to +-1
  float e = __expf(2.f * y);
  return 1.f - 2.f * __builtin_amdgcn_rcpf(e + 1.f);
}
__device__ inline float fast_sigmoid(float z) {
  return __builtin_amdgcn_rcpf(1.f + __expf(-z));
}

// ---- fp32 -> bf16 cast, 8 elems/thread ----
__global__ __launch_bounds__(256) void cast_bf16_kernel(
    const float* __restrict__ in, unsigned short* __restrict__ out, int n8) {
  int i = blockIdx.x * 256 + threadIdx.x;
  if (i >= n8) return;
  float4 a = ((const float4*)in)[2 * i];
  float4 b = ((const float4*)in)[2 * i + 1];
  unsigned short t[8] = {f2bf(a.x), f2bf(a.y), f2bf(a.z), f2bf(a.w),
                         f2bf(b.x), f2bf(b.y), f2bf(b.z), f2bf(b.w)};
  ((uint4*)out)[i] = *(const uint4*)t;
}

// ---- W [768][256] fp32 -> WT [256][768] bf16 ----
__global__ __launch_bounds__(256) void transpose_cast_kernel(
    const float* __restrict__ W, unsigned short* __restrict__ WT) {
  const int k0 = blockIdx.x * 8, o = threadIdx.x;
  unsigned short t[8];
#pragma unroll
  for (int j = 0; j < 8; ++j) t[j] = f2bf(W[(k0 + j) * OUTF + o]);
  *(uint4*)&WT[o * 768 + k0] = *(const uint4*)t;
}

// ---- bf16 MFMA GEMM: C[BT x 256] = A[BT x K] @ B[K x 256] (+bias)(+act) ----
// A split across two sources (A1: first K1S*32 cols, A2: rest). B passed as
// B^T rows: Bt[col*ldb + k] bf16. BM=64, BN=64, 4 waves; wave w -> rows w*16..
template <int KSTEPS, int K1S, bool OUT_BF16, int ACT>
__global__ __launch_bounds__(256) void mfma_gemm_kernel(
    const unsigned short* __restrict__ A1,
    const unsigned short* __restrict__ A2,
    const unsigned short* __restrict__ Bt, int ldb,
    const float* __restrict__ bias, void* __restrict__ Cout) {
  constexpr int LDA1 = K1S * 32;
  constexpr int LDA2 = (KSTEPS - K1S) * 32;
  __shared__ unsigned short As[64 * 40];  // stride 40 elems (80B, 16B-aligned)

  const int tid = threadIdx.x;
  const int row0 = blockIdx.x * 64;
  const int col0 = blockIdx.y * 64;
  const int w = tid >> 6, lane = tid & 63;
  const int lr = lane & 15, kg = lane >> 4;  // frag row/col & k-group

  f32x4 acc[4] = {{0.f, 0.f, 0.f, 0.f},
                  {0.f, 0.f, 0.f, 0.f},
                  {0.f, 0.f, 0.f, 0.f},
                  {0.f, 0.f, 0.f, 0.f}};

  const int sr = tid >> 2;          // staging row 0..63
  const int sc = (tid & 3) * 8;     // staging col 0,8,16,24

  for (int kk = 0; kk < KSTEPS; ++kk) {
    // stage A tile [64][32] bf16
    const unsigned short* src;
    int idx;
    if (kk < K1S) {
      src = A1;
      idx = (row0 + sr) * LDA1 + kk * 32 + sc;
    } else {
      src = A2;
      idx = (row0 + sr) * LDA2 + (kk - K1S) * 32 + sc;
    }
    *(uint4*)&As[sr * 40 + sc] = *(const uint4*)(src + idx);
    __syncthreads();

    bf16x8 a = *(const bf16x8*)&As[(w * 16 + lr) * 40 + kg * 8];
#pragma unroll
    for (int f = 0; f < 4; ++f) {
      const unsigned short* bp =
          Bt + (size_t)(col0 + f * 16 + lr) * ldb + kk * 32 + kg * 8;
      bf16x8 b = *(const bf16x8*)bp;
      acc[f] = __builtin_amdgcn_mfma_f32_16x16x32_bf16(a, b, acc[f], 0, 0, 0);
    }
    __syncthreads();
  }

  // epilogue: C/D layout col=lane&15, row=(lane>>4)*4+r  [m89-verified]
#pragma unroll
  for (int f = 0; f < 4; ++f) {
    const int col = col0 + f * 16 + lr;
    const float bb = bias ? bias[col] : 0.f;
#pragma unroll
    for (int r = 0; r < 4; ++r) {
      const int row = row0 + w * 16 + kg * 4 + r;
      float val = acc[f][r] + bb;
      if (ACT == 1) val = fast_sigmoid(val);
      if (OUT_BF16)
        ((unsigned short*)Cout)[(size_t)row * OUTF + col] = f2bf(val);
      else
        ((float*)Cout)[(size_t)row * OUTF + col] = val;
    }
  }
}

// ---- attention core: one block per (b,t) ----
__global__ __launch_bounds__(256) void attn_kernel(
    const unsigned short* __restrict__ xwh_b,   // [BT,256] bf16 (bias folded)
    const unsigned short* __restrict__ encwe_b, // [BT,256] bf16
    const unsigned short* __restrict__ encb,    // [BT,256] bf16
    const float* __restrict__ v,                // [256]
    unsigned short* __restrict__ wtd_b,         // [BT,256] bf16 (aliases xwh_b)
    float* __restrict__ a_out) {                // [BT,33]
  __shared__ float s_xwh[OUTF];
  __shared__ float s_v[OUTF];
  __shared__ float s_sc[WIN];
  __shared__ float s_a[WIN];

  const int tid = threadIdx.x;
  const int bt = blockIdx.x;
  const int b = bt / T_DIM, t = bt % T_DIM;

  s_xwh[tid] = bf2f(xwh_b[(size_t)bt * OUTF + tid]);
  s_v[tid] = v[tid];
  __syncthreads();

  const int wv = tid >> 6, lane = tid & 63;
  const float4 xv = *(const float4*)&s_xwh[lane * 4];
  const float4 vv = *(const float4*)&s_v[lane * 4];

  for (int w = wv; w < WIN; w += 4) {
    const int t2 = t + w - WSZ;
    float acc;
    if (t2 >= 0 && t2 < T_DIM) {
      ushort4 e4 = *(const ushort4*)&encwe_b[(size_t)(b * T_DIM + t2) * OUTF + lane * 4];
      acc = fast_tanh(xv.x + bf2f(e4.x)) * vv.x;
      acc += fast_tanh(xv.y + bf2f(e4.y)) * vv.y;
      acc += fast_tanh(xv.z + bf2f(e4.z)) * vv.z;
      acc += fast_tanh(xv.w + bf2f(e4.w)) * vv.w;
    } else {
      acc = fast_tanh(xv.x) * vv.x + fast_tanh(xv.y) * vv.y +
            fast_tanh(xv.z) * vv.z + fast_tanh(xv.w) * vv.w;
    }
#pragma unroll
    for (int off = 32; off; off >>= 1) acc += __shfl_xor(acc, off);
    if (lane == 0) s_sc[w] = acc;
  }
  __syncthreads();

  if (tid < 64) {
    const float sc = (tid < WIN) ? s_sc[tid] : -INFINITY;
    float m = sc;
#pragma unroll
    for (int off = 32; off; off >>= 1) m = fmaxf(m, __shfl_xor(m, off));
    float e = (tid < WIN) ? __expf(sc - m) : 0.f;
    float s = e;
#pragma unroll
    for (int off = 32; off; off >>= 1) s += __shfl_xor(s, off);
    const float av = e * __builtin_amdgcn_rcpf(s);
    if (tid < WIN) {
      s_a[tid] = av;
      a_out[(size_t)bt * WIN + tid] = av;
    }
  }
  __syncthreads();

  float acc = 0.f;
#pragma unroll
  for (int w = 0; w < WIN; ++w) {
    const int t2 = t + w - WSZ;
    if (t2 >= 0 && t2 < T_DIM)
      acc = fmaf(s_a[w], bf2f(encb[(size_t)(b * T_DIM + t2) * OUTF + tid]), acc);
  }
  wtd_b[(size_t)bt * OUTF + tid] = f2bf(acc);
}

extern "C" void kernel_launch(void* const* d_in, const int* in_sizes, int n_in,
                              void* d_out, int out_size, void* d_ws,
                              size_t ws_size, hipStream_t stream) {
  const float* x      = (const float*)d_in[0];  // [4,2048,512]
  const float* enc    = (const float*)d_in[1];  // [4,2048,256]
  const float* W_attn = (const float*)d_in[2];  // [768,256]
  const float* b_attn = (const float*)d_in[3];  // [256]
  const float* v      = (const float*)d_in[4];  // [256]
  const float* W_lin  = (const float*)d_in[5];  // [768,256]
  const float* b_lin  = (const float*)d_in[6];  // [256]

  float* out   = (float*)d_out;            // [BT,256]
  float* a_out = out + (size_t)BT * OUTF;  // [BT,33]

  // workspace (bf16, 20.75 MB total)
  unsigned short* xb    = (unsigned short*)d_ws;       // BT*512
  unsigned short* encb  = xb + (size_t)BT * MODEL;     // BT*256
  unsigned short* wtT   = encb + (size_t)BT * OUTF;    // 256*768 (W_attn^T)
  unsigned short* wlT   = wtT + 768 * OUTF;            // 256*768 (W_lin^T)
  unsigned short* xwh   = wlT + 768 * OUTF;            // BT*256 (later = wtd)
  unsigned short* encwe = xwh + (size_t)BT * OUTF;     // BT*256

  cast_bf16_kernel<<<(BT * MODEL / 8 + 255) / 256, 256, 0, stream>>>(x, xb, BT * MODEL / 8);
  cast_bf16_kernel<<<(BT * OUTF / 8 + 255) / 256, 256, 0, stream>>>(enc, encb, BT * OUTF / 8);
  transpose_cast_kernel<<<96, 256, 0, stream>>>(W_attn, wtT);
  transpose_cast_kernel<<<96, 256, 0, stream>>>(W_lin, wlT);

  // xWh = x @ Wh + b_attn   (bf16 out)
  mfma_gemm_kernel<16, 16, true, 0><<<dim3(128, 4), 256, 0, stream>>>(
      xb, nullptr, wtT, 768, b_attn, xwh);
  // encWe = enc @ We        (bf16 out); We^T = rows of wtT at k-offset 512
  mfma_gemm_kernel<8, 8, true, 0><<<dim3(128, 4), 256, 0, stream>>>(
      encb, nullptr, wtT + 512, 768, nullptr, encwe);
  // attention (writes wtd into the xwh buffer + a output)
  attn_kernel<<<BT, 256, 0, stream>>>(xwh, encwe, encb, v, xwh, a_out);
  // out = sigmoid([x | wtd] @ W_lin + b_lin)   (fp32 out)
  mfma_gemm_kernel<24, 16, false, 1><<<dim3(128, 4), 256, 0, stream>>>(
      xb, xwh, wlT, 768, b_lin, out);
}

// Round 3
// 99.383 us; speedup vs baseline: 2.4505x; 1.5226x over previous
//
#include <hip/hip_runtime.h>
#include <math.h>

#define T_DIM 2048
#define B_DIM 4
#define BT (B_DIM * T_DIM)
#define MODEL 512
#define OUTF 256
#define WSZ 16
#define WIN 33

typedef __attribute__((ext_vector_type(8))) short bf16x8;
typedef __attribute__((ext_vector_type(4))) float f32x4;

__device__ inline unsigned short f2bf(float f) {
  unsigned int u = __float_as_uint(f);
  u += 0x7fffu + ((u >> 16) & 1u);  // RNE
  return (unsigned short)(u >> 16);
}
__device__ inline float bflo(unsigned int u) {  // low bf16 of a u32 pair
  return __uint_as_float(u << 16);
}
__device__ inline float bfhi(unsigned int u) {  // high bf16 of a u32 pair
  return __uint_as_float(u & 0xffff0000u);
}
__device__ inline float fast_sigmoid(float z) {
  return __builtin_amdgcn_rcpf(1.f + __expf(-z));
}

// ---- fused prep: cast x->bf16, cast enc->bf16, transpose+cast both W ----
__global__ __launch_bounds__(256) void prep_kernel(
    const float* __restrict__ x, const float* __restrict__ enc,
    const float* __restrict__ W_attn, const float* __restrict__ W_lin,
    unsigned short* __restrict__ xb, unsigned short* __restrict__ encb,
    unsigned short* __restrict__ wtT, unsigned short* __restrict__ wlT) {
  const int bid = blockIdx.x, tid = threadIdx.x;
  if (bid < 3072) {  // casts
    const float* src = (bid < 2048) ? x : enc;
    unsigned short* dst = (bid < 2048) ? xb : encb;
    const int i = (bid < 2048 ? bid : bid - 2048) * 256 + tid;
    float4 a = ((const float4*)src)[2 * i];
    float4 b = ((const float4*)src)[2 * i + 1];
    unsigned short t[8] = {f2bf(a.x), f2bf(a.y), f2bf(a.z), f2bf(a.w),
                           f2bf(b.x), f2bf(b.y), f2bf(b.z), f2bf(b.w)};
    ((uint4*)dst)[i] = *(const uint4*)t;
  } else {  // W [768][256] fp32 -> WT [256][768] bf16
    const float* W = (bid < 3168) ? W_attn : W_lin;
    unsigned short* WT = (bid < 3168) ? wtT : wlT;
    const int k0 = ((bid < 3168) ? bid - 3072 : bid - 3168) * 8, o = tid;
    unsigned short t[8];
#pragma unroll
    for (int j = 0; j < 8; ++j) t[j] = f2bf(W[(k0 + j) * OUTF + o]);
    *(uint4*)&WT[o * 768 + k0] = *(const uint4*)t;
  }
}

// ---- bf16 MFMA GEMM, 64x64 tile, dbuf LDS, T14 load-early/write-late ----
// A = [A1 rows of K1S*32 | A2 rows of (KSTEPS-K1S)*32] bf16. Bt = B^T rows.
template <int KSTEPS, int K1S, bool OUT_BF16, int ACT>
__global__ __launch_bounds__(256) void mfma_gemm_kernel(
    const unsigned short* __restrict__ A1,
    const unsigned short* __restrict__ A2,
    const unsigned short* __restrict__ Bt, int ldb,
    const float* __restrict__ bias, void* __restrict__ Cout, float oscale) {
  constexpr int LDA1 = K1S * 32;
  constexpr int LDA2 = (KSTEPS - K1S) * 32;
  __shared__ unsigned short As[2][64 * 40];

  const int tid = threadIdx.x;
  const int row0 = blockIdx.x * 64, col0 = blockIdx.y * 64;
  const int w = tid >> 6, lane = tid & 63;
  const int lr = lane & 15, kg = lane >> 4;
  const int sr = tid >> 2, sc = (tid & 3) * 8;

  auto aload = [&](int kk) -> uint4 {
    if (K1S > 0 && kk < K1S)
      return *(const uint4*)(A1 + (size_t)(row0 + sr) * LDA1 + kk * 32 + sc);
    return *(const uint4*)(A2 + (size_t)(row0 + sr) * LDA2 +
                           (size_t)(kk - K1S) * 32 + sc);
  };

  f32x4 acc[4] = {{0.f, 0.f, 0.f, 0.f},
                  {0.f, 0.f, 0.f, 0.f},
                  {0.f, 0.f, 0.f, 0.f},
                  {0.f, 0.f, 0.f, 0.f}};

  uint4 rg = aload(0);
  *(uint4*)&As[0][sr * 40 + sc] = rg;
  __syncthreads();

  for (int kk = 0; kk < KSTEPS; ++kk) {
    const bool more = (kk + 1 < KSTEPS);
    if (more) rg = aload(kk + 1);  // issue early; lands during MFMA
    bf16x8 a = *(const bf16x8*)&As[kk & 1][(w * 16 + lr) * 40 + kg * 8];
#pragma unroll
    for (int f = 0; f < 4; ++f) {
      bf16x8 bfrag = *(const bf16x8*)(Bt + (size_t)(col0 + f * 16 + lr) * ldb +
                                      kk * 32 + kg * 8);
      acc[f] = __builtin_amdgcn_mfma_f32_16x16x32_bf16(a, bfrag, acc[f], 0, 0, 0);
    }
    if (more) *(uint4*)&As[(kk + 1) & 1][sr * 40 + sc] = rg;  // write late
    __syncthreads();
  }

  // C/D layout: col=lane&15, row=(lane>>4)*4+r  [m89-verified]
#pragma unroll
  for (int f = 0; f < 4; ++f) {
    const int col = col0 + f * 16 + lr;
    const float bb = bias ? bias[col] : 0.f;
#pragma unroll
    for (int r = 0; r < 4; ++r) {
      const int row = row0 + w * 16 + kg * 4 + r;
      float val = (acc[f][r] + bb) * oscale;
      if (ACT == 1) val = fast_sigmoid(val);
      if (OUT_BF16)
        ((unsigned short*)Cout)[(size_t)row * OUTF + col] = f2bf(val);
      else
        ((float*)Cout)[(size_t)row * OUTF + col] = val;
    }
  }
}

// ---- attention core: one WAVE per (b,t); 4 independent waves per block ----
// xwh2 = 2*(x@Wh+b_attn), encwe2 = 2*(enc@We), both bf16.
// score(w) = sum_o tanh(.)*v[o] = Vsum - 2*S(w), S = sum v[o]*rcp(e^{2y}+1)
// softmax(score) == softmax(-2S)  (Vsum constant per t).
__global__ __launch_bounds__(256) void attn_kernel(
    const unsigned short* __restrict__ xwh2,
    const unsigned short* __restrict__ encwe2,
    const unsigned short* __restrict__ encb,
    const float* __restrict__ v,
    unsigned short* __restrict__ wtd,   // aliases xwh2 buffer (row bt only)
    float* __restrict__ a_out) {
  const int lane = threadIdx.x & 63;
  const int wv = threadIdx.x >> 6;
  // XCD-grouping swizzle: each XCD gets 1024 consecutive t (2048 % 8 == 0)
  const int bs = ((blockIdx.x & 7) << 8) | (blockIdx.x >> 3);
  const int bt = bs * 4 + wv;
  const int b = bt >> 11, t = bt & (T_DIM - 1);
  const int g = lane >> 4, sl = lane & 15;
  const size_t rowbase = (size_t)bt * OUTF;

  // lane's o-range for the score phase: [sl*16, sl*16+16)
  float xf[16], vf[16];
  {
    const uint4* xp = (const uint4*)(xwh2 + rowbase + sl * 16);
    uint4 q0 = xp[0], q1 = xp[1];
    unsigned int uw[8] = {q0.x, q0.y, q0.z, q0.w, q1.x, q1.y, q1.z, q1.w};
#pragma unroll
    for (int j = 0; j < 8; ++j) {
      xf[2 * j] = bflo(uw[j]);
      xf[2 * j + 1] = bfhi(uw[j]);
    }
    const float4* vp = (const float4*)(v + sl * 16);
#pragma unroll
    for (int j = 0; j < 4; ++j) {
      float4 t4 = vp[j];
      vf[4 * j] = t4.x; vf[4 * j + 1] = t4.y;
      vf[4 * j + 2] = t4.z; vf[4 * j + 3] = t4.w;
    }
  }

  // ---- scores: 9 chunks x 4 windows, manual next-chunk prefetch ----
  float my_s = 0.f;
  uint4 e0, e1;
  bool valid;
  {
    const int w0i = g, t2 = t + w0i - WSZ;
    valid = ((unsigned)t2 < T_DIM);
    const int t2c = valid ? t2 : t;
    const uint4* ep = (const uint4*)(encwe2 + (size_t)(b * T_DIM + t2c) * OUTF + sl * 16);
    e0 = ep[0]; e1 = ep[1];
  }
  for (int c = 0; c < 9; ++c) {
    uint4 c0 = e0, c1 = e1;
    const bool cval = valid;
    if (c < 8) {  // prefetch chunk c+1
      const int wn = (c + 1) * 4 + g, t2 = t + wn - WSZ;
      valid = (wn < WIN) && ((unsigned)t2 < T_DIM);
      const int t2c = valid ? t2 : t;
      const uint4* ep = (const uint4*)(encwe2 + (size_t)(b * T_DIM + t2c) * OUTF + sl * 16);
      e0 = ep[0]; e1 = ep[1];
    }
    if (!cval) { c0 = make_uint4(0, 0, 0, 0); c1 = make_uint4(0, 0, 0, 0); }
    unsigned int ew[8] = {c0.x, c0.y, c0.z, c0.w, c1.x, c1.y, c1.z, c1.w};
    float acc = 0.f;
#pragma unroll
    for (int j = 0; j < 8; ++j) {
      float ylo = xf[2 * j] + bflo(ew[j]);
      float yhi = xf[2 * j + 1] + bfhi(ew[j]);
      float rlo = __builtin_amdgcn_rcpf(__expf(ylo) + 1.f);
      float rhi = __builtin_amdgcn_rcpf(__expf(yhi) + 1.f);
      acc = fmaf(vf[2 * j], rlo, acc);
      acc = fmaf(vf[2 * j + 1], rhi, acc);
    }
    // sum over the 16 lanes of this window's group (butterfly)
#pragma unroll
    for (int off = 1; off < 16; off <<= 1) acc += __shfl_xor(acc, off);
    // route score for window w to lane w
    float cand = __shfl(acc, (lane & 3) << 4);
    if ((lane >> 2) == c) my_s = cand;
  }

  // ---- softmax over 33 (lane l holds S for window l); score = -2S ----
  float Sm = (lane < WIN) ? my_s : INFINITY;
#pragma unroll
  for (int off = 1; off < 64; off <<= 1) Sm = fminf(Sm, __shfl_xor(Sm, off));
  float p = (lane < WIN) ? __expf(2.f * (Sm - my_s)) : 0.f;
  float sum = p;
#pragma unroll
  for (int off = 1; off < 64; off <<= 1) sum += __shfl_xor(sum, off);
  const float aval = p * __builtin_amdgcn_rcpf(sum);
  if (lane < WIN) a_out[(size_t)bt * WIN + lane] = aval;

  // ---- weighted[f] = sum_w a[w] * enc[b, t+w-16, f]; lane owns 4 o ----
  const int o4 = lane * 4;
  float acc0 = 0.f, acc1 = 0.f, acc2 = 0.f, acc3 = 0.f;
#pragma unroll
  for (int ww = 0; ww < WIN; ++ww) {
    const int t2 = t + ww - WSZ;
    const bool val2 = ((unsigned)t2 < T_DIM);
    float aw = __shfl(aval, ww);
    aw = val2 ? aw : 0.f;
    const int t2c = val2 ? t2 : t;
    const uint2 e2 = *(const uint2*)(encb + (size_t)(b * T_DIM + t2c) * OUTF + o4);
    acc0 = fmaf(aw, bflo(e2.x), acc0);
    acc1 = fmaf(aw, bfhi(e2.x), acc1);
    acc2 = fmaf(aw, bflo(e2.y), acc2);
    acc3 = fmaf(aw, bfhi(e2.y), acc3);
  }
  uint2 pk;
  pk.x = (unsigned int)f2bf(acc0) | ((unsigned int)f2bf(acc1) << 16);
  pk.y = (unsigned int)f2bf(acc2) | ((unsigned int)f2bf(acc3) << 16);
  *(uint2*)(wtd + rowbase + o4) = pk;
}

extern "C" void kernel_launch(void* const* d_in, const int* in_sizes, int n_in,
                              void* d_out, int out_size, void* d_ws,
                              size_t ws_size, hipStream_t stream) {
  const float* x      = (const float*)d_in[0];  // [4,2048,512]
  const float* enc    = (const float*)d_in[1];  // [4,2048,256]
  const float* W_attn = (const float*)d_in[2];  // [768,256]
  const float* b_attn = (const float*)d_in[3];  // [256]
  const float* v      = (const float*)d_in[4];  // [256]
  const float* W_lin  = (const float*)d_in[5];  // [768,256]
  const float* b_lin  = (const float*)d_in[6];  // [256]

  float* out   = (float*)d_out;            // [BT,256]
  float* a_out = out + (size_t)BT * OUTF;  // [BT,33]

  unsigned short* xb     = (unsigned short*)d_ws;     // BT*512
  unsigned short* encb   = xb + (size_t)BT * MODEL;   // BT*256
  unsigned short* wtT    = encb + (size_t)BT * OUTF;  // 256*768
  unsigned short* wlT    = wtT + 768 * OUTF;          // 256*768
  unsigned short* xwh2   = wlT + 768 * OUTF;          // BT*256 (later wtd)
  unsigned short* encwe2 = xwh2 + (size_t)BT * OUTF;  // BT*256

  // one fused prep launch: cast x, cast enc, transpose both weights
  prep_kernel<<<3264, 256, 0, stream>>>(x, enc, W_attn, W_lin, xb, encb, wtT, wlT);

  // xwh2 = 2*(x @ Wh + b_attn)
  mfma_gemm_kernel<16, 16, true, 0><<<dim3(128, 4), 256, 0, stream>>>(
      xb, nullptr, wtT, 768, b_attn, xwh2, 2.0f);
  // encwe2 = 2*(enc @ We)
  mfma_gemm_kernel<8, 0, true, 0><<<dim3(128, 4), 256, 0, stream>>>(
      nullptr, encb, wtT + 512, 768, nullptr, encwe2, 2.0f);
  // attention (writes wtd into xwh2 buffer + a output)
  attn_kernel<<<BT / 4, 256, 0, stream>>>(xwh2, encwe2, encb, v, xwh2, a_out);
  // out = sigmoid([x | wtd] @ W_lin + b_lin)
  mfma_gemm_kernel<24, 16, false, 1><<<dim3(128, 4), 256, 0, stream>>>(
      xb, xwh2, wlT, 768, b_lin, out, 1.0f);
}

// Round 4
// 79.423 us; speedup vs baseline: 3.0664x; 1.2513x over previous
//
#include <hip/hip_runtime.h>
#include <math.h>

#define T_DIM 2048
#define B_DIM 4
#define BT (B_DIM * T_DIM)
#define MODEL 512
#define OUTF 256
#define WSZ 16
#define WIN 33

typedef __attribute__((ext_vector_type(8))) short bf16x8;
typedef __attribute__((ext_vector_type(4))) float f32x4;

__device__ inline unsigned short f2bf(float f) {
  unsigned int u = __float_as_uint(f);
  u += 0x7fffu + ((u >> 16) & 1u);  // RNE
  return (unsigned short)(u >> 16);
}
__device__ inline float bflo(unsigned int u) {
  return __uint_as_float(u << 16);
}
__device__ inline float bfhi(unsigned int u) {
  return __uint_as_float(u & 0xffff0000u);
}
__device__ inline float fast_sigmoid(float z) {
  return __builtin_amdgcn_rcpf(1.f + __expf(-z));
}

// ---- fused prep: cast x->bf16, cast enc->bf16, transpose+cast both W ----
__global__ __launch_bounds__(256) void prep_kernel(
    const float* __restrict__ x, const float* __restrict__ enc,
    const float* __restrict__ W_attn, const float* __restrict__ W_lin,
    unsigned short* __restrict__ xb, unsigned short* __restrict__ encb,
    unsigned short* __restrict__ wtT, unsigned short* __restrict__ wlT) {
  const int bid = blockIdx.x, tid = threadIdx.x;
  if (bid < 3072) {  // casts
    const float* src = (bid < 2048) ? x : enc;
    unsigned short* dst = (bid < 2048) ? xb : encb;
    const int i = (bid < 2048 ? bid : bid - 2048) * 256 + tid;
    float4 a = ((const float4*)src)[2 * i];
    float4 b = ((const float4*)src)[2 * i + 1];
    unsigned short t[8] = {f2bf(a.x), f2bf(a.y), f2bf(a.z), f2bf(a.w),
                           f2bf(b.x), f2bf(b.y), f2bf(b.z), f2bf(b.w)};
    ((uint4*)dst)[i] = *(const uint4*)t;
  } else {  // W [768][256] fp32 -> WT [256][768] bf16
    const float* W = (bid < 3168) ? W_attn : W_lin;
    unsigned short* WT = (bid < 3168) ? wtT : wlT;
    const int k0 = ((bid < 3168) ? bid - 3072 : bid - 3168) * 8, o = tid;
    unsigned short t[8];
#pragma unroll
    for (int j = 0; j < 8; ++j) t[j] = f2bf(W[(k0 + j) * OUTF + o]);
    *(uint4*)&WT[o * 768 + k0] = *(const uint4*)t;
  }
}

// ---- panel GEMM: B-panel (64 cols x K) resident in LDS, loaded once;
// A fragments streamed global->regs; K-loop has ZERO barriers.
// MODE 0: dual output — yy<4: outb = f2bf(2*(acc+biasA)) [xwh2]
//                       yy>=4: outf = acc+biasB (fp32)     [z1]
// MODE 1: outb = f2bf(2*acc)                               [encwe2]
// MODE 2: outf = sigmoid(acc + zin)                        [final out]
// XCD-swizzled 1D grid: rbid -> (xcd=rbid&7, s=rbid>>3), i = xcd*16+s/NY.
template <int KSTEPS, int MODE>
__global__ __launch_bounds__(256) void gemm_kernel(
    const unsigned short* __restrict__ A, int lda,
    const unsigned short* __restrict__ BtA,
    const unsigned short* __restrict__ BtB,
    const float* __restrict__ biasA, const float* __restrict__ biasB,
    unsigned short* __restrict__ outb, float* __restrict__ outf,
    const float* __restrict__ zin) {
  constexpr int K = KSTEPS * 32;
  constexpr int NY = (MODE == 0) ? 8 : 4;
  __shared__ unsigned short Bs[64 * K];  // 64KB (K=512) / 32KB (K=256)

  const int tid = threadIdx.x;
  const int rbid = blockIdx.x;
  const int xcd = rbid & 7, s = rbid >> 3;
  const int i = xcd * 16 + s / NY;
  const int yy = s % NY;
  const int row0 = i * 64;
  const int col0 = (yy & 3) * 64;

  const unsigned short* Bt = (MODE == 0 && yy >= 4) ? BtB : BtA;

  // stage B panel with XOR swizzle (G4: 16-lane stride-K reads would be
  // 16-way conflicts; e ^= (c&7)<<3 spreads rows across banks)
  for (int idx = tid; idx < 64 * (K / 8); idx += 256) {
    const int c = idx / (K / 8), kc = idx % (K / 8);
    const int e = (c * K + kc * 8) ^ ((c & 7) << 3);
    *(uint4*)&Bs[e] = *(const uint4*)(Bt + (size_t)(col0 + c) * 768 + kc * 8);
  }
  __syncthreads();

  const int w = tid >> 6, lane = tid & 63;
  const int lr = lane & 15, kg = lane >> 4;

  f32x4 acc[4] = {{0.f, 0.f, 0.f, 0.f},
                  {0.f, 0.f, 0.f, 0.f},
                  {0.f, 0.f, 0.f, 0.f},
                  {0.f, 0.f, 0.f, 0.f}};

  const unsigned short* arow = A + (size_t)(row0 + w * 16 + lr) * lda + kg * 8;
  const int bxor = (lr & 7) << 3;
#pragma unroll
  for (int kk = 0; kk < KSTEPS; ++kk) {
    bf16x8 a = *(const bf16x8*)(arow + kk * 32);
#pragma unroll
    for (int f = 0; f < 4; ++f) {
      const int e = ((f * 16 + lr) * K + kk * 32 + kg * 8) ^ bxor;
      bf16x8 b = *(const bf16x8*)&Bs[e];
      acc[f] = __builtin_amdgcn_mfma_f32_16x16x32_bf16(a, b, acc[f], 0, 0, 0);
    }
  }

  // C/D layout: col=lane&15, row=(lane>>4)*4+r  [m89-verified]
#pragma unroll
  for (int f = 0; f < 4; ++f) {
    const int col = col0 + f * 16 + lr;
#pragma unroll
    for (int r = 0; r < 4; ++r) {
      const int row = row0 + w * 16 + kg * 4 + r;
      float val = acc[f][r];
      if (MODE == 0) {
        if (yy < 4)
          outb[(size_t)row * OUTF + col] = f2bf((val + biasA[col]) * 2.f);
        else
          outf[(size_t)row * OUTF + col] = val + biasB[col];
      } else if (MODE == 1) {
        outb[(size_t)row * OUTF + col] = f2bf(val * 2.f);
      } else {
        outf[(size_t)row * OUTF + col] =
            fast_sigmoid(val + zin[(size_t)row * OUTF + col]);
      }
    }
  }
}

// ---- attention core: one WAVE per (b,t); 4 independent waves per block ----
// xwh2 = 2*(x@Wh+b_attn), encwe2 = 2*(enc@We), both bf16.
// score(w) = Vsum - 2*S(w), S = sum v[o]*rcp(e^{2y}+1); softmax==softmax(-2S)
__global__ __launch_bounds__(256) void attn_kernel(
    const unsigned short* __restrict__ xwh2,
    const unsigned short* __restrict__ encwe2,
    const unsigned short* __restrict__ encb,
    const float* __restrict__ v,
    unsigned short* __restrict__ wtd,   // aliases xwh2 buffer (row bt only)
    float* __restrict__ a_out) {
  const int lane = threadIdx.x & 63;
  const int wv = threadIdx.x >> 6;
  const int bs = ((blockIdx.x & 7) << 8) | (blockIdx.x >> 3);
  const int bt = bs * 4 + wv;
  const int b = bt >> 11, t = bt & (T_DIM - 1);
  const int g = lane >> 4, sl = lane & 15;
  const size_t rowbase = (size_t)bt * OUTF;

  float xf[16], vf[16];
  {
    const uint4* xp = (const uint4*)(xwh2 + rowbase + sl * 16);
    uint4 q0 = xp[0], q1 = xp[1];
    unsigned int uw[8] = {q0.x, q0.y, q0.z, q0.w, q1.x, q1.y, q1.z, q1.w};
#pragma unroll
    for (int j = 0; j < 8; ++j) {
      xf[2 * j] = bflo(uw[j]);
      xf[2 * j + 1] = bfhi(uw[j]);
    }
    const float4* vp = (const float4*)(v + sl * 16);
#pragma unroll
    for (int j = 0; j < 4; ++j) {
      float4 t4 = vp[j];
      vf[4 * j] = t4.x; vf[4 * j + 1] = t4.y;
      vf[4 * j + 2] = t4.z; vf[4 * j + 3] = t4.w;
    }
  }

  float my_s = 0.f;
  uint4 e0, e1;
  bool valid;
  {
    const int t2 = t + g - WSZ;
    valid = ((unsigned)t2 < T_DIM);
    const int t2c = valid ? t2 : t;
    const uint4* ep = (const uint4*)(encwe2 + (size_t)(b * T_DIM + t2c) * OUTF + sl * 16);
    e0 = ep[0]; e1 = ep[1];
  }
  for (int c = 0; c < 9; ++c) {
    uint4 c0 = e0, c1 = e1;
    const bool cval = valid;
    if (c < 8) {
      const int wn = (c + 1) * 4 + g, t2 = t + wn - WSZ;
      valid = (wn < WIN) && ((unsigned)t2 < T_DIM);
      const int t2c = valid ? t2 : t;
      const uint4* ep = (const uint4*)(encwe2 + (size_t)(b * T_DIM + t2c) * OUTF + sl * 16);
      e0 = ep[0]; e1 = ep[1];
    }
    if (!cval) { c0 = make_uint4(0, 0, 0, 0); c1 = make_uint4(0, 0, 0, 0); }
    unsigned int ew[8] = {c0.x, c0.y, c0.z, c0.w, c1.x, c1.y, c1.z, c1.w};
    float acc = 0.f;
#pragma unroll
    for (int j = 0; j < 8; ++j) {
      float ylo = xf[2 * j] + bflo(ew[j]);
      float yhi = xf[2 * j + 1] + bfhi(ew[j]);
      float rlo = __builtin_amdgcn_rcpf(__expf(ylo) + 1.f);
      float rhi = __builtin_amdgcn_rcpf(__expf(yhi) + 1.f);
      acc = fmaf(vf[2 * j], rlo, acc);
      acc = fmaf(vf[2 * j + 1], rhi, acc);
    }
#pragma unroll
    for (int off = 1; off < 16; off <<= 1) acc += __shfl_xor(acc, off);
    float cand = __shfl(acc, (lane & 3) << 4);
    if ((lane >> 2) == c) my_s = cand;
  }

  float Sm = (lane < WIN) ? my_s : INFINITY;
#pragma unroll
  for (int off = 1; off < 64; off <<= 1) Sm = fminf(Sm, __shfl_xor(Sm, off));
  float p = (lane < WIN) ? __expf(2.f * (Sm - my_s)) : 0.f;
  float sum = p;
#pragma unroll
  for (int off = 1; off < 64; off <<= 1) sum += __shfl_xor(sum, off);
  const float aval = p * __builtin_amdgcn_rcpf(sum);
  if (lane < WIN) a_out[(size_t)bt * WIN + lane] = aval;

  const int o4 = lane * 4;
  float acc0 = 0.f, acc1 = 0.f, acc2 = 0.f, acc3 = 0.f;
#pragma unroll
  for (int ww = 0; ww < WIN; ++ww) {
    const int t2 = t + ww - WSZ;
    const bool val2 = ((unsigned)t2 < T_DIM);
    float aw = __shfl(aval, ww);
    aw = val2 ? aw : 0.f;
    const int t2c = val2 ? t2 : t;
    const uint2 e2 = *(const uint2*)(encb + (size_t)(b * T_DIM + t2c) * OUTF + o4);
    acc0 = fmaf(aw, bflo(e2.x), acc0);
    acc1 = fmaf(aw, bfhi(e2.x), acc1);
    acc2 = fmaf(aw, bflo(e2.y), acc2);
    acc3 = fmaf(aw, bfhi(e2.y), acc3);
  }
  uint2 pk;
  pk.x = (unsigned int)f2bf(acc0) | ((unsigned int)f2bf(acc1) << 16);
  pk.y = (unsigned int)f2bf(acc2) | ((unsigned int)f2bf(acc3) << 16);
  *(uint2*)(wtd + rowbase + o4) = pk;
}

extern "C" void kernel_launch(void* const* d_in, const int* in_sizes, int n_in,
                              void* d_out, int out_size, void* d_ws,
                              size_t ws_size, hipStream_t stream) {
  const float* x      = (const float*)d_in[0];  // [4,2048,512]
  const float* enc    = (const float*)d_in[1];  // [4,2048,256]
  const float* W_attn = (const float*)d_in[2];  // [768,256]
  const float* b_attn = (const float*)d_in[3];  // [256]
  const float* v      = (const float*)d_in[4];  // [256]
  const float* W_lin  = (const float*)d_in[5];  // [768,256]
  const float* b_lin  = (const float*)d_in[6];  // [256]

  float* out   = (float*)d_out;            // [BT,256]
  float* a_out = out + (size_t)BT * OUTF;  // [BT,33]

  unsigned short* xb     = (unsigned short*)d_ws;     // BT*512
  unsigned short* encb   = xb + (size_t)BT * MODEL;   // BT*256
  unsigned short* wtT    = encb + (size_t)BT * OUTF;  // 256*768
  unsigned short* wlT    = wtT + 768 * OUTF;          // 256*768
  unsigned short* xwh2   = wlT + 768 * OUTF;          // BT*256 (later wtd)
  unsigned short* encwe2 = xwh2 + (size_t)BT * OUTF;  // BT*256
  float*          z1     = (float*)(encwe2 + (size_t)BT * OUTF);  // BT*256 f32

  // fused prep: cast x, cast enc, transpose both weights
  prep_kernel<<<3264, 256, 0, stream>>>(x, enc, W_attn, W_lin, xb, encb, wtT, wlT);

  // gemmA: x @ [Wh | Wl1]  ->  xwh2 (bf16, x2, +b_attn) and z1 (f32, +b_lin)
  gemm_kernel<16, 0><<<1024, 256, 0, stream>>>(
      xb, MODEL, wtT, wlT, b_attn, b_lin, xwh2, z1, nullptr);
  // gemmB: enc @ We -> encwe2 (bf16, x2)
  gemm_kernel<8, 1><<<512, 256, 0, stream>>>(
      encb, OUTF, wtT + 512, nullptr, nullptr, nullptr, encwe2, nullptr, nullptr);
  // attention (writes wtd into xwh2 buffer + a output)
  attn_kernel<<<BT / 4, 256, 0, stream>>>(xwh2, encwe2, encb, v, xwh2, a_out);
  // gemmC: out = sigmoid(z1 + wtd @ Wl2)
  gemm_kernel<8, 2><<<512, 256, 0, stream>>>(
      xwh2, OUTF, wlT + 512, nullptr, nullptr, nullptr, nullptr, out, z1);
}

// Round 5
// 78.063 us; speedup vs baseline: 3.1198x; 1.0174x over previous
//
#include <hip/hip_runtime.h>
#include <math.h>

#define T_DIM 2048
#define B_DIM 4
#define BT (B_DIM * T_DIM)
#define MODEL 512
#define OUTF 256
#define WSZ 16
#define WIN 33

// 2*log2(e): xwh2/encwe2 are stored pre-scaled so attn uses raw v_exp_f32.
#define ESCALE 2.885390081777927f

typedef __attribute__((ext_vector_type(8))) short bf16x8;
typedef __attribute__((ext_vector_type(4))) float f32x4;

__device__ inline unsigned short f2bf(float f) {
  unsigned int u = __float_as_uint(f);
  u += 0x7fffu + ((u >> 16) & 1u);  // RNE
  return (unsigned short)(u >> 16);
}
__device__ inline float bflo(unsigned int u) {
  return __uint_as_float(u << 16);
}
__device__ inline float bfhi(unsigned int u) {
  return __uint_as_float(u & 0xffff0000u);
}
__device__ inline float fast_sigmoid(float z) {
  return __builtin_amdgcn_rcpf(1.f + __expf(-z));
}

// ---- fused prep: cast x->bf16, cast enc->bf16, transpose+cast both W ----
__global__ __launch_bounds__(256) void prep_kernel(
    const float* __restrict__ x, const float* __restrict__ enc,
    const float* __restrict__ W_attn, const float* __restrict__ W_lin,
    unsigned short* __restrict__ xb, unsigned short* __restrict__ encb,
    unsigned short* __restrict__ wtT, unsigned short* __restrict__ wlT) {
  const int bid = blockIdx.x, tid = threadIdx.x;
  if (bid < 3072) {  // casts
    const float* src = (bid < 2048) ? x : enc;
    unsigned short* dst = (bid < 2048) ? xb : encb;
    const int i = (bid < 2048 ? bid : bid - 2048) * 256 + tid;
    float4 a = ((const float4*)src)[2 * i];
    float4 b = ((const float4*)src)[2 * i + 1];
    unsigned short t[8] = {f2bf(a.x), f2bf(a.y), f2bf(a.z), f2bf(a.w),
                           f2bf(b.x), f2bf(b.y), f2bf(b.z), f2bf(b.w)};
    ((uint4*)dst)[i] = *(const uint4*)t;
  } else {  // W [768][256] fp32 -> WT [256][768] bf16
    const float* W = (bid < 3168) ? W_attn : W_lin;
    unsigned short* WT = (bid < 3168) ? wtT : wlT;
    const int k0 = ((bid < 3168) ? bid - 3072 : bid - 3168) * 8, o = tid;
    unsigned short t[8];
#pragma unroll
    for (int j = 0; j < 8; ++j) t[j] = f2bf(W[(k0 + j) * OUTF + o]);
    *(uint4*)&WT[o * 768 + k0] = *(const uint4*)t;
  }
}

// ---- panel GEMM body: 32KB B-panel per stage (K=256), XOR-swizzled LDS;
// A fragments streamed global->regs; barrier only at stage boundaries.
// MODE 0: dual out — yy<4: outb=f2bf((acc+biasA)*ESCALE); yy>=4: outf=acc+biasB
// MODE 1: outb=f2bf(acc*ESCALE)
// MODE 2: outf=sigmoid(acc+zin)
template <int STAGES, int MODE>
__device__ __forceinline__ void gemm_body(
    unsigned short* Bs, int rbid,
    const unsigned short* __restrict__ A, int lda,
    const unsigned short* __restrict__ BtA,
    const unsigned short* __restrict__ BtB,
    const float* __restrict__ biasA, const float* __restrict__ biasB,
    unsigned short* __restrict__ outb, float* __restrict__ outf,
    const float* __restrict__ zin) {
  constexpr int KC = 256;  // K per stage
  constexpr int NY = (MODE == 0) ? 8 : 4;
  const int tid = threadIdx.x;
  const int xcd = rbid & 7, s = rbid >> 3;
  const int i = xcd * 16 + s / NY;
  const int yy = s % NY;
  const int row0 = i * 64;
  const int col0 = (yy & 3) * 64;

  const unsigned short* Bt = (MODE == 0 && yy >= 4) ? BtB : BtA;

  const int w = tid >> 6, lane = tid & 63;
  const int lr = lane & 15, kg = lane >> 4;
  const unsigned short* arow = A + (size_t)(row0 + w * 16 + lr) * lda + kg * 8;
  const int bxor = (lr & 7) << 3;

  f32x4 acc[4] = {{0.f, 0.f, 0.f, 0.f},
                  {0.f, 0.f, 0.f, 0.f},
                  {0.f, 0.f, 0.f, 0.f},
                  {0.f, 0.f, 0.f, 0.f}};

#pragma unroll
  for (int st = 0; st < STAGES; ++st) {
    if (st) __syncthreads();
    // stage 64 cols x 256 k (swizzle: e ^= (c&7)<<3 spreads banks)
    for (int idx = tid; idx < 64 * (KC / 8); idx += 256) {
      const int c = idx >> 5, kc = idx & 31;
      const int e = (c * KC + kc * 8) ^ ((c & 7) << 3);
      *(uint4*)&Bs[e] =
          *(const uint4*)(Bt + (size_t)(col0 + c) * 768 + st * KC + kc * 8);
    }
    __syncthreads();

#pragma unroll
    for (int kk = 0; kk < 8; ++kk) {
      bf16x8 a = *(const bf16x8*)(arow + (st * 8 + kk) * 32);
#pragma unroll
      for (int f = 0; f < 4; ++f) {
        const int e = ((f * 16 + lr) * KC + kk * 32 + kg * 8) ^ bxor;
        bf16x8 b = *(const bf16x8*)&Bs[e];
        acc[f] = __builtin_amdgcn_mfma_f32_16x16x32_bf16(a, b, acc[f], 0, 0, 0);
      }
    }
  }

  // C/D layout: col=lane&15, row=(lane>>4)*4+r  [m89-verified]
#pragma unroll
  for (int f = 0; f < 4; ++f) {
    const int col = col0 + f * 16 + lr;
#pragma unroll
    for (int r = 0; r < 4; ++r) {
      const int row = row0 + w * 16 + kg * 4 + r;
      float val = acc[f][r];
      if (MODE == 0) {
        if (yy < 4)
          outb[(size_t)row * OUTF + col] = f2bf((val + biasA[col]) * ESCALE);
        else
          outf[(size_t)row * OUTF + col] = val + biasB[col];
      } else if (MODE == 1) {
        outb[(size_t)row * OUTF + col] = f2bf(val * ESCALE);
      } else {
        outf[(size_t)row * OUTF + col] =
            fast_sigmoid(val + zin[(size_t)row * OUTF + col]);
      }
    }
  }
}

// merged launch: blocks [0,1024) = x@[Wh|Wl1]; [1024,1536) = enc@We
__global__ __launch_bounds__(256) void gemmAB_kernel(
    const unsigned short* __restrict__ xb, const unsigned short* __restrict__ encb,
    const unsigned short* __restrict__ wtT, const unsigned short* __restrict__ wlT,
    const float* __restrict__ b_attn, const float* __restrict__ b_lin,
    unsigned short* __restrict__ xwh2, float* __restrict__ z1,
    unsigned short* __restrict__ encwe2) {
  __shared__ unsigned short Bs[64 * 256];
  if (blockIdx.x < 1024)
    gemm_body<2, 0>(Bs, blockIdx.x, xb, MODEL, wtT, wlT, b_attn, b_lin,
                    xwh2, z1, nullptr);
  else
    gemm_body<1, 1>(Bs, blockIdx.x - 1024, encb, OUTF, wtT + 512, nullptr,
                    nullptr, nullptr, encwe2, nullptr, nullptr);
}

__global__ __launch_bounds__(256) void gemmC_kernel(
    const unsigned short* __restrict__ wtd, const unsigned short* __restrict__ wlT,
    float* __restrict__ out, const float* __restrict__ z1) {
  __shared__ unsigned short Bs[64 * 256];
  gemm_body<1, 2>(Bs, blockIdx.x, wtd, OUTF, wlT + 512, nullptr, nullptr,
                  nullptr, nullptr, out, z1);
}

// ---- attention core: one WAVE per (b,t); 4 independent waves per block ----
// xwh2 = ESCALE*(x@Wh+b_attn), encwe2 = ESCALE*(enc@We); y = xf+e = 2z*log2e
// S = sum v*rcp(2^y+1) computed PAIRWISE (1 rcp / 2 elems, y clamped <=21.5)
// softmax(score) == softmax(-2S)
__global__ __launch_bounds__(256) void attn_kernel(
    const unsigned short* __restrict__ xwh2,
    const unsigned short* __restrict__ encwe2,
    const unsigned short* __restrict__ encb,
    const float* __restrict__ v,
    unsigned short* __restrict__ wtd,   // aliases xwh2 buffer (row bt only)
    float* __restrict__ a_out) {
  const int lane = threadIdx.x & 63;
  const int wv = threadIdx.x >> 6;
  const int bs = ((blockIdx.x & 7) << 8) | (blockIdx.x >> 3);
  const int bt = bs * 4 + wv;
  const int b = bt >> 11, t = bt & (T_DIM - 1);
  const int g = lane >> 4, sl = lane & 15;
  const size_t rowbase = (size_t)bt * OUTF;

  float xf[16], vf[16];
  {
    const uint4* xp = (const uint4*)(xwh2 + rowbase + sl * 16);
    uint4 q0 = xp[0], q1 = xp[1];
    unsigned int uw[8] = {q0.x, q0.y, q0.z, q0.w, q1.x, q1.y, q1.z, q1.w};
#pragma unroll
    for (int j = 0; j < 8; ++j) {
      xf[2 * j] = bflo(uw[j]);
      xf[2 * j + 1] = bfhi(uw[j]);
    }
    const float4* vp = (const float4*)(v + sl * 16);
#pragma unroll
    for (int j = 0; j < 4; ++j) {
      float4 t4 = vp[j];
      vf[4 * j] = t4.x; vf[4 * j + 1] = t4.y;
      vf[4 * j + 2] = t4.z; vf[4 * j + 3] = t4.w;
    }
  }

  float my_s = 0.f;
  uint4 e0, e1;
  bool valid;
  {
    const int t2 = t + g - WSZ;
    valid = ((unsigned)t2 < T_DIM);
    const int t2c = valid ? t2 : t;
    const uint4* ep = (const uint4*)(encwe2 + (size_t)(b * T_DIM + t2c) * OUTF + sl * 16);
    e0 = ep[0]; e1 = ep[1];
  }
  for (int c = 0; c < 9; ++c) {
    uint4 c0 = e0, c1 = e1;
    const bool cval = valid;
    if (c < 8) {
      const int wn = (c + 1) * 4 + g, t2 = t + wn - WSZ;
      valid = (wn < WIN) && ((unsigned)t2 < T_DIM);
      const int t2c = valid ? t2 : t;
      const uint4* ep = (const uint4*)(encwe2 + (size_t)(b * T_DIM + t2c) * OUTF + sl * 16);
      e0 = ep[0]; e1 = ep[1];
    }
    if (!cval) { c0 = make_uint4(0, 0, 0, 0); c1 = make_uint4(0, 0, 0, 0); }
    unsigned int ew[8] = {c0.x, c0.y, c0.z, c0.w, c1.x, c1.y, c1.z, c1.w};
    float acc = 0.f;
#pragma unroll
    for (int j = 0; j < 8; ++j) {
      // pair-rcp: v0/(1+E0) + v1/(1+E1) = [ (v0+v1) + v0*E1 + v1*E0 ] /
      //                                   [ (1+E0)(1+E1) ],  E = 2^y
      const float v0 = vf[2 * j], v1 = vf[2 * j + 1];
      float ylo = fminf(xf[2 * j] + bflo(ew[j]), 21.5f);
      float yhi = fminf(xf[2 * j + 1] + bfhi(ew[j]), 21.5f);
      float elo = __builtin_amdgcn_exp2f(ylo);
      float ehi = __builtin_amdgcn_exp2f(yhi);
      float den = (elo + 1.f) * (ehi + 1.f);
      float num = fmaf(v0, ehi, v0 + v1);
      num = fmaf(v1, elo, num);
      acc = fmaf(num, __builtin_amdgcn_rcpf(den), acc);
    }
#pragma unroll
    for (int off = 1; off < 16; off <<= 1) acc += __shfl_xor(acc, off);
    float cand = __shfl(acc, (lane & 3) << 4);
    if ((lane >> 2) == c) my_s = cand;
  }

  float Sm = (lane < WIN) ? my_s : INFINITY;
#pragma unroll
  for (int off = 1; off < 64; off <<= 1) Sm = fminf(Sm, __shfl_xor(Sm, off));
  float p = (lane < WIN) ? __expf(2.f * (Sm - my_s)) : 0.f;
  float sum = p;
#pragma unroll
  for (int off = 1; off < 64; off <<= 1) sum += __shfl_xor(sum, off);
  const float aval = p * __builtin_amdgcn_rcpf(sum);
  if (lane < WIN) a_out[(size_t)bt * WIN + lane] = aval;

  const int o4 = lane * 4;
  float acc0 = 0.f, acc1 = 0.f, acc2 = 0.f, acc3 = 0.f;
#pragma unroll
  for (int ww = 0; ww < WIN; ++ww) {
    const int t2 = t + ww - WSZ;
    const bool val2 = ((unsigned)t2 < T_DIM);
    float aw = __shfl(aval, ww);
    aw = val2 ? aw : 0.f;
    const int t2c = val2 ? t2 : t;
    const uint2 e2 = *(const uint2*)(encb + (size_t)(b * T_DIM + t2c) * OUTF + o4);
    acc0 = fmaf(aw, bflo(e2.x), acc0);
    acc1 = fmaf(aw, bfhi(e2.x), acc1);
    acc2 = fmaf(aw, bflo(e2.y), acc2);
    acc3 = fmaf(aw, bfhi(e2.y), acc3);
  }
  uint2 pk;
  pk.x = (unsigned int)f2bf(acc0) | ((unsigned int)f2bf(acc1) << 16);
  pk.y = (unsigned int)f2bf(acc2) | ((unsigned int)f2bf(acc3) << 16);
  *(uint2*)(wtd + rowbase + o4) = pk;
}

extern "C" void kernel_launch(void* const* d_in, const int* in_sizes, int n_in,
                              void* d_out, int out_size, void* d_ws,
                              size_t ws_size, hipStream_t stream) {
  const float* x      = (const float*)d_in[0];  // [4,2048,512]
  const float* enc    = (const float*)d_in[1];  // [4,2048,256]
  const float* W_attn = (const float*)d_in[2];  // [768,256]
  const float* b_attn = (const float*)d_in[3];  // [256]
  const float* v      = (const float*)d_in[4];  // [256]
  const float* W_lin  = (const float*)d_in[5];  // [768,256]
  const float* b_lin  = (const float*)d_in[6];  // [256]

  float* out   = (float*)d_out;            // [BT,256]
  float* a_out = out + (size_t)BT * OUTF;  // [BT,33]

  unsigned short* xb     = (unsigned short*)d_ws;     // BT*512
  unsigned short* encb   = xb + (size_t)BT * MODEL;   // BT*256
  unsigned short* wtT    = encb + (size_t)BT * OUTF;  // 256*768
  unsigned short* wlT    = wtT + 768 * OUTF;          // 256*768
  unsigned short* xwh2   = wlT + 768 * OUTF;          // BT*256 (later wtd)
  unsigned short* encwe2 = xwh2 + (size_t)BT * OUTF;  // BT*256
  float*          z1     = (float*)(encwe2 + (size_t)BT * OUTF);  // BT*256 f32

  // fused prep: cast x, cast enc, transpose both weights
  prep_kernel<<<3264, 256, 0, stream>>>(x, enc, W_attn, W_lin, xb, encb, wtT, wlT);
  // gemmA (x@[Wh|Wl1] -> xwh2,z1) + gemmB (enc@We -> encwe2), one launch
  gemmAB_kernel<<<1536, 256, 0, stream>>>(xb, encb, wtT, wlT, b_attn, b_lin,
                                          xwh2, z1, encwe2);
  // attention (writes wtd into xwh2 buffer + a output)
  attn_kernel<<<BT / 4, 256, 0, stream>>>(xwh2, encwe2, encb, v, xwh2, a_out);
  // gemmC: out = sigmoid(z1 + wtd @ Wl2)
  gemmC_kernel<<<512, 256, 0, stream>>>(xwh2, wlT, out, z1);
}